// Round 9
// baseline (328.587 us; speedup 1.0000x reference)
//
#include <hip/hip_runtime.h>

// ---------------------------------------------------------------------------
// GIN 2-layer forward. R9: one kernel per GIN layer — gather-aggregate into
// LDS (phase 0), then fused MLP (GEMM->ReLU->GEMM) from LDS. Kills g0/g1
// round-trips; gather latency overlaps MFMA across co-resident blocks.
// bf16 MFMA (16x16x32), CSR gather, hierarchical scan.
// N=50000, E=600000, dims 128->256->256->256->128.
// ---------------------------------------------------------------------------

typedef __bf16 bf16x8 __attribute__((ext_vector_type(8)));
typedef float f32x4 __attribute__((ext_vector_type(4)));
typedef unsigned short u16x8 __attribute__((ext_vector_type(8)));
typedef unsigned short u16x4 __attribute__((ext_vector_type(4)));
typedef unsigned int uint32;

__device__ __forceinline__ unsigned short f2bf(float f) {
  uint32 u = __builtin_bit_cast(uint32, f);
  u += 0x7FFFu + ((u >> 16) & 1u);  // RNE
  return (unsigned short)(u >> 16);
}
__device__ __forceinline__ float bf2f(unsigned short h) {
  return __builtin_bit_cast(float, (uint32)h << 16);
}

#define G2L16(gp, lp)                                                        \
  __builtin_amdgcn_global_load_lds(                                          \
      (const __attribute__((address_space(1))) void*)(gp),                   \
      (__attribute__((address_space(3))) void*)(lp), 16, 0, 0)

// ---------------------------- CSR build ------------------------------------
__global__ void hist(const int* __restrict__ eidx, int* __restrict__ deg, int E) {
  int e = blockIdx.x * blockDim.x + threadIdx.x;
  if (e < E) atomicAdd(&deg[eidx[e + E]], 1);
}

__global__ __launch_bounds__(256) void block_sums(const int* __restrict__ deg,
                                                  int* __restrict__ bsum, int Nn) {
  __shared__ int sm[256];
  int t = threadIdx.x;
  int i = blockIdx.x * 256 + t;
  sm[t] = (i < Nn) ? deg[i] : 0;
  __syncthreads();
#pragma unroll
  for (int off = 128; off > 0; off >>= 1) {
    if (t < off) sm[t] += sm[t + off];
    __syncthreads();
  }
  if (t == 0) bsum[blockIdx.x] = sm[0];
}

__global__ __launch_bounds__(256) void scan_bsums(int* __restrict__ bsum, int nb) {
  __shared__ int sm[256];
  int t = threadIdx.x;
  int v = (t < nb) ? bsum[t] : 0;
  sm[t] = v;
  __syncthreads();
#pragma unroll
  for (int off = 1; off < 256; off <<= 1) {
    int add = (t >= off) ? sm[t - off] : 0;
    __syncthreads();
    sm[t] += add;
    __syncthreads();
  }
  if (t < nb) bsum[t] = sm[t] - v;  // exclusive
}

__global__ __launch_bounds__(256) void block_scan(const int* __restrict__ deg,
                                                  const int* __restrict__ bsum,
                                                  int* __restrict__ offs,
                                                  int* __restrict__ pos, int Nn) {
  __shared__ int sm[256];
  int t = threadIdx.x;
  int i = blockIdx.x * 256 + t;
  int v = (i < Nn) ? deg[i] : 0;
  sm[t] = v;
  __syncthreads();
#pragma unroll
  for (int off = 1; off < 256; off <<= 1) {
    int add = (t >= off) ? sm[t - off] : 0;
    __syncthreads();
    sm[t] += add;
    __syncthreads();
  }
  int ex = bsum[blockIdx.x] + sm[t] - v;
  if (i < Nn) {
    offs[i] = ex;
    pos[i] = ex;
    if (i == Nn - 1) offs[Nn] = ex + v;
  }
}

__global__ void fill_csr(const int* __restrict__ eidx, int* __restrict__ pos,
                         int* __restrict__ esrc, int E) {
  int e = blockIdx.x * blockDim.x + threadIdx.x;
  if (e < E) {
    int s = eidx[e];
    int d = eidx[e + E];
    int p = atomicAdd(&pos[d], 1);
    esrc[p] = s;
  }
}

// --------------- fused prep: zero deg + cast x->bf16 + transposes -----------
__global__ __launch_bounds__(256) void prep(
    int* __restrict__ deg, int Nn,
    const float* __restrict__ x, unsigned short* __restrict__ xb, long long n4,
    const float* __restrict__ W1a, const float* __restrict__ W2a,
    const float* __restrict__ W1b, const float* __restrict__ W2b,
    unsigned short* __restrict__ w1t, unsigned short* __restrict__ w2t,
    unsigned short* __restrict__ w3t, unsigned short* __restrict__ w4t) {
  int zb = (Nn + 255) >> 8;
  int b = blockIdx.x;
  int t = threadIdx.x;
  if (b < zb) {
    int i = b * 256 + t;
    if (i < Nn) deg[i] = 0;
  } else if (b < zb + 768) {
    int i = (b - zb) * 256 + t;  // 0..196607
    const float* W;
    unsigned short* WT;
    int K, N, j;
    if (i < 32768) {            // W1a: 128x256
      W = W1a; WT = w1t; K = 128; N = 256; j = i;
    } else if (i < 98304) {     // W2a: 256x256
      W = W2a; WT = w2t; K = 256; N = 256; j = i - 32768;
    } else if (i < 163840) {    // W1b: 256x256
      W = W1b; WT = w3t; K = 256; N = 256; j = i - 98304;
    } else {                    // W2b: 256x128
      W = W2b; WT = w4t; K = 256; N = 128; j = i - 163840;
    }
    int k = j / N, n = j - k * N;
    WT[n * K + k] = f2bf(W[j]);
  } else {
    long long i = (long long)(b - zb - 768) * 256 + t;
    long long stride = (long long)(gridDim.x - zb - 768) * 256;
    for (; i < n4; i += stride) {
      float4 v = ((const float4*)x)[i];
      u16x4 o;
      o.x = f2bf(v.x); o.y = f2bf(v.y); o.z = f2bf(v.z); o.w = f2bf(v.w);
      ((u16x4*)xb)[i] = o;
    }
  }
}

// ----------------------- fused GIN layer -----------------------------------
// out = relu?( relu( agg(X) @ W1 + b1 ) @ W2 + b2 )
// X bf16 [M][D] (gather source); BT1 bf16 [256][D]; BT2 bf16 [N2][256].
// Block = 64 nodes. Phase 0: 4 waves gather-aggregate 16 nodes each into
// LDS Xs (ld-padded). Stage 1: Xs @ W1 -> Ts (aliases Xs; dead after
// stage 1). Stage 2: Ts @ W2 -> out.
template <int D, int N2, bool OUT_BF16>
__global__ __launch_bounds__(256) void fused_gin(
    const unsigned short* __restrict__ X,
    const int* __restrict__ offs, const int* __restrict__ esrc,
    const unsigned short* __restrict__ BT1, const float* __restrict__ b1,
    const unsigned short* __restrict__ BT2, const float* __restrict__ b2,
    void* __restrict__ Cout, int M) {
  constexpr int LDT = 264;                     // Ts leading dim (64x264)
  constexpr int LDX = (D == 128) ? 136 : 264;  // Xs leading dim (+4-bank skew)
  __shared__ unsigned short Ts[64 * LDT];      // 33.8 KB; Xs aliases this
  __shared__ unsigned short Bs[256 * 32];      // 16 KB
  unsigned short* Xs = Ts;
  const int tid = threadIdx.x;
  const int wave = tid >> 6, lane = tid & 63;
  const int quad = lane >> 4, l16 = lane & 15;
  const int rowBase = blockIdx.x * 64;

  // ---- phase 0: gather-aggregate 64 rows into Xs ----
  if (D == 128) {
    int grp = lane >> 4;  // 4 rows per load instr
    int l = lane & 15;
    const unsigned short* xp = X + l * 8;
    for (int i = 0; i < 16; ++i) {
      int cn = min(rowBase + wave * 16 + i, M - 1);
      int beg = offs[cn], end = offs[cn + 1];
      int total = end - beg + 1;  // incl. self
      float acc[8] = {};
      for (int j0 = 0; j0 < total; j0 += 16) {
#pragma unroll
        for (int u = 0; u < 4; ++u) {
          int j = j0 + u * 4 + grp;
          int rv = esrc[beg + j - (j > 0)];  // ≤ +16 past end (pad absorbed)
          long long row = (j > 0 && j < total) ? rv : cn;
          float sel = (j < total) ? 1.f : 0.f;
          u16x8 v = *(const u16x8*)(xp + row * D);
#pragma unroll
          for (int k = 0; k < 8; ++k) acc[k] = fmaf(bf2f(v[k]), sel, acc[k]);
        }
      }
#pragma unroll
      for (int k = 0; k < 8; ++k) acc[k] += __shfl_xor(acc[k], 16);
#pragma unroll
      for (int k = 0; k < 8; ++k) acc[k] += __shfl_xor(acc[k], 32);
      if (grp == 0) {
        u16x8 o;
#pragma unroll
        for (int k = 0; k < 8; ++k) o[k] = f2bf(acc[k]);
        *(u16x8*)(Xs + (wave * 16 + i) * LDX + l * 8) = o;
      }
    }
  } else {
    int grp = lane >> 5;  // 2 rows per load instr
    int l = lane & 31;
    const unsigned short* xp = X + l * 8;
    for (int i = 0; i < 16; ++i) {
      int cn = min(rowBase + wave * 16 + i, M - 1);
      int beg = offs[cn], end = offs[cn + 1];
      int total = end - beg + 1;
      float acc[8] = {};
      for (int j0 = 0; j0 < total; j0 += 16) {
#pragma unroll
        for (int u = 0; u < 8; ++u) {
          int j = j0 + u * 2 + grp;
          int rv = esrc[beg + j - (j > 0)];
          long long row = (j > 0 && j < total) ? rv : cn;
          float sel = (j < total) ? 1.f : 0.f;
          u16x8 v = *(const u16x8*)(xp + row * D);
#pragma unroll
          for (int k = 0; k < 8; ++k) acc[k] = fmaf(bf2f(v[k]), sel, acc[k]);
        }
      }
#pragma unroll
      for (int k = 0; k < 8; ++k) acc[k] += __shfl_xor(acc[k], 32);
      if (grp == 0) {
        u16x8 o;
#pragma unroll
        for (int k = 0; k < 8; ++k) o[k] = f2bf(acc[k]);
        *(u16x8*)(Xs + (wave * 16 + i) * LDX + l * 8) = o;
      }
    }
  }
  __syncthreads();

  // ---- stage 1: T = relu(Xs @ W1 + b1) ----
  const int r16 = lane >> 2;
  const int kq = lane & 3;
  const unsigned short* gb = BT1 + (long long)(wave * 64 + r16) * D + kq * 8;
  f32x4 acc1[4][4] = {};
  for (int k0 = 0; k0 < D; k0 += 32) {
#pragma unroll
    for (int c = 0; c < 4; ++c)
      G2L16(gb + (long long)(16 * c) * D, Bs + (wave * 64 + 16 * c) * 32);
    gb += 32;
    __syncthreads();
    bf16x8 af[4], bfr[4];
#pragma unroll
    for (int mi = 0; mi < 4; ++mi)
      af[mi] = *(const bf16x8*)(Xs + (mi * 16 + l16) * LDX + k0 + quad * 8);
#pragma unroll
    for (int ni = 0; ni < 4; ++ni)
      bfr[ni] = *(const bf16x8*)(Bs + (wave * 64 + ni * 16 + l16) * 32 + quad * 8);
#pragma unroll
    for (int mi = 0; mi < 4; ++mi)
#pragma unroll
      for (int ni = 0; ni < 4; ++ni)
        acc1[mi][ni] = __builtin_amdgcn_mfma_f32_16x16x32_bf16(
            af[mi], bfr[ni], acc1[mi][ni], 0, 0, 0);
    __syncthreads();
  }
  // epilogue 1 -> Ts (safe: Xs dead after final loop barrier)
#pragma unroll
  for (int ni = 0; ni < 4; ++ni) {
    int col = wave * 64 + ni * 16 + l16;
    float bv = b1[col];
#pragma unroll
    for (int mi = 0; mi < 4; ++mi)
#pragma unroll
      for (int r = 0; r < 4; ++r) {
        int row = mi * 16 + quad * 4 + r;
        Ts[row * LDT + col] = f2bf(fmaxf(acc1[mi][ni][r] + bv, 0.f));
      }
  }
  __syncthreads();

  // ---- stage 2: C = Ts @ W2 + b2 ----
  constexpr int NI2 = N2 / 64;
  const int wcol = wave * (N2 / 4);
  const unsigned short* gb2 = BT2 + (long long)(wcol + r16) * 256 + kq * 8;
  f32x4 acc2[4][NI2] = {};
  for (int k2 = 0; k2 < 256; k2 += 32) {
#pragma unroll
    for (int c = 0; c < NI2; ++c)
      G2L16(gb2 + (long long)(16 * c) * 256, Bs + (wcol + 16 * c) * 32);
    gb2 += 32;
    __syncthreads();
    bf16x8 af[4], bfr[NI2];
#pragma unroll
    for (int mi = 0; mi < 4; ++mi)
      af[mi] = *(const bf16x8*)(Ts + (mi * 16 + l16) * LDT + k2 + quad * 8);
#pragma unroll
    for (int ni = 0; ni < NI2; ++ni)
      bfr[ni] = *(const bf16x8*)(Bs + (wcol + ni * 16 + l16) * 32 + quad * 8);
#pragma unroll
    for (int mi = 0; mi < 4; ++mi)
#pragma unroll
      for (int ni = 0; ni < NI2; ++ni)
        acc2[mi][ni] = __builtin_amdgcn_mfma_f32_16x16x32_bf16(
            af[mi], bfr[ni], acc2[mi][ni], 0, 0, 0);
    __syncthreads();
  }
  // epilogue 2
#pragma unroll
  for (int ni = 0; ni < NI2; ++ni) {
    int col = wcol + ni * 16 + l16;
    float bv = b2[col];
#pragma unroll
    for (int mi = 0; mi < 4; ++mi)
#pragma unroll
      for (int r = 0; r < 4; ++r) {
        int row = rowBase + mi * 16 + quad * 4 + r;
        if (row < M) {
          float o = acc2[mi][ni][r] + bv;
          if (OUT_BF16)
            ((unsigned short*)Cout)[(long long)row * N2 + col] = f2bf(fmaxf(o, 0.f));
          else
            ((float*)Cout)[(long long)row * N2 + col] = o;
        }
      }
  }
}

// ---------------------------------------------------------------------------
extern "C" void kernel_launch(void* const* d_in, const int* in_sizes, int n_in,
                              void* d_out, int out_size, void* d_ws, size_t ws_size,
                              hipStream_t stream) {
  const float* x   = (const float*)d_in[0];
  const float* W1a = (const float*)d_in[1];
  const float* b1a = (const float*)d_in[2];
  const float* W2a = (const float*)d_in[3];
  const float* b2a = (const float*)d_in[4];
  const float* W1b = (const float*)d_in[5];
  const float* b1b = (const float*)d_in[6];
  const float* W2b = (const float*)d_in[7];
  const float* b2b = (const float*)d_in[8];
  const int*   ei  = (const int*)d_in[9];  // [2,E]: row0=src, row1=dst

  const int Nn = in_sizes[0] / 128;  // 50000
  const int E  = in_sizes[9] / 2;    // 600000
  float* out = (float*)d_out;

  // workspace
  unsigned short* h   = (unsigned short*)d_ws;     // N*256 bf16
  unsigned short* xb  = h  + (size_t)Nn * 256;     // N*128
  unsigned short* w1t = xb + (size_t)Nn * 128;     // 256*128
  unsigned short* w2t = w1t + 256 * 128;           // 256*256
  unsigned short* w3t = w2t + 256 * 256;           // 256*256
  unsigned short* w4t = w3t + 256 * 256;           // 128*256
  int* deg  = (int*)(w4t + 128 * 256);
  int* offs = deg + Nn;        // N+1
  int* pos  = offs + Nn + 1;   // N
  int* esrc = pos + Nn;        // E
  int* bsum = esrc + E;        // ~196 (also absorbs agg index overshoot)

  dim3 blk(256);
  int nb = (Nn + 255) / 256;  // 196 scan blocks

  // prep: zero deg + cast x->bf16 + weight transposes (one launch)
  prep<<<nb + 768 + 2048, blk, 0, stream>>>(deg, Nn, x, xb,
                                            (long long)Nn * 128 / 4,
                                            W1a, W2a, W1b, W2b,
                                            w1t, w2t, w3t, w4t);
  // CSR build
  hist<<<(E + 255) / 256, blk, 0, stream>>>(ei, deg, E);
  block_sums<<<nb, blk, 0, stream>>>(deg, bsum, Nn);
  scan_bsums<<<1, blk, 0, stream>>>(bsum, nb);
  block_scan<<<nb, blk, 0, stream>>>(deg, bsum, offs, pos, Nn);
  fill_csr<<<(E + 255) / 256, blk, 0, stream>>>(ei, pos, esrc, E);

  int gb = (Nn + 63) / 64;  // 782 blocks

  // layer 0: h = relu(mlp(agg(xb)))
  fused_gin<128, 256, true><<<gb, blk, 0, stream>>>(
      xb, offs, esrc, w1t, b1a, w2t, b2a, h, Nn);
  // layer 1: out = mlp(agg(h))
  fused_gin<256, 128, false><<<gb, blk, 0, stream>>>(
      h, offs, esrc, w3t, b1b, w4t, b2b, out, Nn);
}

// Round 10
// 293.474 us; speedup vs baseline: 1.1196x; 1.1196x over previous
//
#include <hip/hip_runtime.h>

// ---------------------------------------------------------------------------
// GIN 2-layer forward. R10: revert R9 fusion (gather needs occupancy, MFMA
// needs LDS — separate kernels). R8 structure + single-kernel CSR scan
// (all-blocks-resident, device-scope atomic flags) + packed f32x2 agg math.
// 8 dispatches total. bf16 MFMA (16x16x32), CSR gather, fused MLPs.
// N=50000, E=600000, dims 128->256->256->256->128.
// ---------------------------------------------------------------------------

typedef __bf16 bf16x8 __attribute__((ext_vector_type(8)));
typedef float f32x4 __attribute__((ext_vector_type(4)));
typedef float f32x2 __attribute__((ext_vector_type(2)));
typedef unsigned short u16x4 __attribute__((ext_vector_type(4)));
typedef unsigned short u16x8 __attribute__((ext_vector_type(8)));
typedef unsigned int uint32;
typedef uint32 u32x4 __attribute__((ext_vector_type(4)));

__device__ __forceinline__ unsigned short f2bf(float f) {
  uint32 u = __builtin_bit_cast(uint32, f);
  u += 0x7FFFu + ((u >> 16) & 1u);  // RNE
  return (unsigned short)(u >> 16);
}
// two bf16 (packed in a u32) -> two f32: lo via shift, hi via mask (1 instr each)
__device__ __forceinline__ f32x2 bfpair(uint32 w) {
  f32x2 r;
  r.x = __builtin_bit_cast(float, w << 16);
  r.y = __builtin_bit_cast(float, w & 0xFFFF0000u);
  return r;
}

#define G2L16(gp, lp)                                                        \
  __builtin_amdgcn_global_load_lds(                                          \
      (const __attribute__((address_space(1))) void*)(gp),                   \
      (__attribute__((address_space(3))) void*)(lp), 16, 0, 0)

// ---------------------------- CSR build ------------------------------------
__global__ void hist(const int* __restrict__ eidx, int* __restrict__ deg, int E) {
  int e = blockIdx.x * blockDim.x + threadIdx.x;
  if (e < E) atomicAdd(&deg[eidx[e + E]], 1);
}

// Single-kernel exclusive scan. Requires all nb (=196) blocks co-resident
// (nb <= 256 CUs, tiny LDS -> guaranteed). flg[] pre-zeroed by prep.
__global__ __launch_bounds__(256) void scan_all(
    const int* __restrict__ deg, int* __restrict__ offs, int* __restrict__ pos,
    int* __restrict__ aggr, int* __restrict__ incl, int* __restrict__ flg,
    int Nn, int nb) {
  __shared__ int sm[256];
  __shared__ int s_prefix;
  const int t = threadIdx.x;
  const int b = blockIdx.x;
  const int i = b * 256 + t;
  int v = (i < Nn) ? deg[i] : 0;
  sm[t] = v;
  __syncthreads();
#pragma unroll
  for (int off = 1; off < 256; off <<= 1) {
    int add = (t >= off) ? sm[t - off] : 0;
    __syncthreads();
    sm[t] += add;
    __syncthreads();
  }
  if (t == 255) {
    atomicExch(&aggr[b], sm[255]);  // device-scope, coherent publish
    atomicExch(&flg[b], 1);
  }
  if (b == 0) {
    // wait for all block aggregates
    for (int j = t; j < nb; j += 256)
      while (atomicAdd(&flg[j], 0) == 0) __builtin_amdgcn_s_sleep(1);
    __syncthreads();
    // parallel scan of nb aggregates (nb <= 256), publish inclusive prefixes
    int a = (t < nb) ? atomicAdd(&aggr[t], 0) : 0;
    __shared__ int sb[256];
    sb[t] = a;
    __syncthreads();
#pragma unroll
    for (int off = 1; off < 256; off <<= 1) {
      int add = (t >= off) ? sb[t - off] : 0;
      __syncthreads();
      sb[t] += add;
      __syncthreads();
    }
    if (t < nb) atomicExch(&incl[t], sb[t]);
    __syncthreads();
    if (t == 0) atomicExch(&flg[nb], 1);  // done
    if (t == 0) s_prefix = 0;
  } else {
    if (t == 0) {
      while (atomicAdd(&flg[nb], 0) == 0) __builtin_amdgcn_s_sleep(8);
      s_prefix = atomicAdd(&incl[b - 1], 0);
    }
  }
  __syncthreads();
  int ex = s_prefix + sm[t] - v;
  if (i < Nn) {
    offs[i] = ex;
    pos[i] = ex;
    if (i == Nn - 1) offs[Nn] = ex + v;
  }
}

__global__ void fill_csr(const int* __restrict__ eidx, int* __restrict__ pos,
                         int* __restrict__ esrc, int E) {
  int e = blockIdx.x * blockDim.x + threadIdx.x;
  if (e < E) {
    int s = eidx[e];
    int d = eidx[e + E];
    int p = atomicAdd(&pos[d], 1);
    esrc[p] = s;
  }
}

// --------------- fused prep: zero (deg+flg) + cast x + transposes -----------
__global__ __launch_bounds__(256) void prep(
    int* __restrict__ zp, int zn,
    const float* __restrict__ x, unsigned short* __restrict__ xb, long long n4,
    const float* __restrict__ W1a, const float* __restrict__ W2a,
    const float* __restrict__ W1b, const float* __restrict__ W2b,
    unsigned short* __restrict__ w1t, unsigned short* __restrict__ w2t,
    unsigned short* __restrict__ w3t, unsigned short* __restrict__ w4t) {
  int zb = (zn + 255) >> 8;
  int b = blockIdx.x;
  int t = threadIdx.x;
  if (b < zb) {
    int i = b * 256 + t;
    if (i < zn) zp[i] = 0;
  } else if (b < zb + 768) {
    int i = (b - zb) * 256 + t;  // 0..196607
    const float* W;
    unsigned short* WT;
    int K, N, j;
    if (i < 32768) {            // W1a: 128x256
      W = W1a; WT = w1t; K = 128; N = 256; j = i;
    } else if (i < 98304) {     // W2a: 256x256
      W = W2a; WT = w2t; K = 256; N = 256; j = i - 32768;
    } else if (i < 163840) {    // W1b: 256x256
      W = W1b; WT = w3t; K = 256; N = 256; j = i - 98304;
    } else {                    // W2b: 256x128
      W = W2b; WT = w4t; K = 256; N = 128; j = i - 163840;
    }
    int k = j / N, n = j - k * N;
    WT[n * K + k] = f2bf(W[j]);
  } else {
    long long i = (long long)(b - zb - 768) * 256 + t;
    long long stride = (long long)(gridDim.x - zb - 768) * 256;
    for (; i < n4; i += stride) {
      float4 v = ((const float4*)x)[i];
      u16x4 o;
      o.x = f2bf(v.x); o.y = f2bf(v.y); o.z = f2bf(v.z); o.w = f2bf(v.w);
      ((u16x4*)xb)[i] = o;
    }
  }
}

// ------------------------- aggregation -------------------------------------
// D=128: one wave/node; 16 lanes/row (16B/lane), 4 rows/load-instr, 16 in
// flight; packed f32x2 accumulate (v_pk_fma_f32).
__global__ __launch_bounds__(256) void agg_bf16_128(
    unsigned short* __restrict__ out, const unsigned short* __restrict__ xb,
    const int* __restrict__ offs, const int* __restrict__ esrc, int Nn) {
  int node = blockIdx.x * 4 + (threadIdx.x >> 6);
  if (node >= Nn) return;
  int lane = threadIdx.x & 63;
  int grp = lane >> 4, l16 = lane & 15;
  int beg = offs[node], end = offs[node + 1];
  int total = end - beg + 1;  // incl. self
  const unsigned short* xp = xb + l16 * 8;
  f32x2 acc[4] = {};
  for (int j0 = 0; j0 < total; j0 += 16) {
#pragma unroll
    for (int u = 0; u < 4; ++u) {
      int j = j0 + u * 4 + grp;
      int rv = esrc[beg + j - (j > 0)];  // <= +16 past end (ws pad absorbs)
      long long row = (j > 0 && j < total) ? rv : node;
      float sel = (j < total) ? 1.f : 0.f;
      f32x2 fsel = {sel, sel};
      u32x4 w = *(const u32x4*)(xp + row * 128);
#pragma unroll
      for (int k = 0; k < 4; ++k) acc[k] += bfpair(w[k]) * fsel;  // pk_fma
    }
  }
  float s[8];
#pragma unroll
  for (int k = 0; k < 4; ++k) { s[2 * k] = acc[k].x; s[2 * k + 1] = acc[k].y; }
#pragma unroll
  for (int k = 0; k < 8; ++k) s[k] += __shfl_xor(s[k], 16);
#pragma unroll
  for (int k = 0; k < 8; ++k) s[k] += __shfl_xor(s[k], 32);
  if (grp == 0) {
    u16x8 o;
#pragma unroll
    for (int k = 0; k < 8; ++k) o[k] = f2bf(s[k]);
    *(u16x8*)(out + (long long)node * 128 + l16 * 8) = o;
  }
}

// D=256: one wave/node; 32 lanes/row (16B/lane), 2 rows/load-instr, 16 in
// flight; packed f32x2 accumulate.
__global__ __launch_bounds__(256) void agg_bf16_256(
    unsigned short* __restrict__ out, const unsigned short* __restrict__ h,
    const int* __restrict__ offs, const int* __restrict__ esrc, int Nn) {
  int node = blockIdx.x * 4 + (threadIdx.x >> 6);
  if (node >= Nn) return;
  int lane = threadIdx.x & 63;
  int grp = lane >> 5, l32 = lane & 31;
  int beg = offs[node], end = offs[node + 1];
  int total = end - beg + 1;  // incl. self
  const unsigned short* hp = h + l32 * 8;
  f32x2 acc[4] = {};
  for (int j0 = 0; j0 < total; j0 += 16) {
#pragma unroll
    for (int u = 0; u < 8; ++u) {
      int j = j0 + u * 2 + grp;
      int rv = esrc[beg + j - (j > 0)];
      long long row = (j > 0 && j < total) ? rv : node;
      float sel = (j < total) ? 1.f : 0.f;
      f32x2 fsel = {sel, sel};
      u32x4 w = *(const u32x4*)(hp + row * 256);
#pragma unroll
      for (int k = 0; k < 4; ++k) acc[k] += bfpair(w[k]) * fsel;  // pk_fma
    }
  }
  float s[8];
#pragma unroll
  for (int k = 0; k < 4; ++k) { s[2 * k] = acc[k].x; s[2 * k + 1] = acc[k].y; }
#pragma unroll
  for (int k = 0; k < 8; ++k) s[k] += __shfl_xor(s[k], 32);
  if (grp == 0) {
    u16x8 o;
#pragma unroll
    for (int k = 0; k < 8; ++k) o[k] = f2bf(s[k]);
    *(u16x8*)(out + (long long)node * 256 + l32 * 8) = o;
  }
}

// --------------------------- fused MLP (from R8) ----------------------------
template <int K1, int N2, bool OUT_BF16>
__global__ __launch_bounds__(256) void fused_mlp(
    const unsigned short* __restrict__ A,
    const unsigned short* __restrict__ BT1, const float* __restrict__ b1,
    const unsigned short* __restrict__ BT2, const float* __restrict__ b2,
    void* __restrict__ Cout, int M) {
  __shared__ unsigned short As[64 * 32];    // 4 KB
  __shared__ unsigned short Bs[256 * 32];   // 16 KB
  __shared__ unsigned short Ts[64 * 264];   // 33.8 KB
  const int tid = threadIdx.x;
  const int wave = tid >> 6, lane = tid & 63;
  const int quad = lane >> 4, l16 = lane & 15;
  const int rowBase = blockIdx.x * 64;
  const int r16 = lane >> 2;
  const int kq = lane & 3;

  // ---- stage 1: T = relu(A @ W1 + b1) ----
  long long arow = min(rowBase + wave * 16 + r16, M - 1);
  const unsigned short* ga = A + arow * K1 + kq * 8;
  const unsigned short* gb = BT1 + (long long)(wave * 64 + r16) * K1 + kq * 8;
  unsigned short* la = As + wave * 16 * 32;
  f32x4 acc[4][4] = {};
  for (int k0 = 0; k0 < K1; k0 += 32) {
    G2L16(ga, la);
    ga += 32;
#pragma unroll
    for (int c = 0; c < 4; ++c)
      G2L16(gb + (long long)(16 * c) * K1, Bs + (wave * 64 + 16 * c) * 32);
    gb += 32;
    __syncthreads();
    bf16x8 af[4], bfr[4];
#pragma unroll
    for (int mi = 0; mi < 4; ++mi)
      af[mi] = *(const bf16x8*)(As + (mi * 16 + l16) * 32 + quad * 8);
#pragma unroll
    for (int ni = 0; ni < 4; ++ni)
      bfr[ni] = *(const bf16x8*)(Bs + (wave * 64 + ni * 16 + l16) * 32 + quad * 8);
#pragma unroll
    for (int mi = 0; mi < 4; ++mi)
#pragma unroll
      for (int ni = 0; ni < 4; ++ni)
        acc[mi][ni] = __builtin_amdgcn_mfma_f32_16x16x32_bf16(
            af[mi], bfr[ni], acc[mi][ni], 0, 0, 0);
    __syncthreads();
  }
#pragma unroll
  for (int ni = 0; ni < 4; ++ni) {
    int col = wave * 64 + ni * 16 + l16;
    float bv = b1[col];
#pragma unroll
    for (int mi = 0; mi < 4; ++mi)
#pragma unroll
      for (int r = 0; r < 4; ++r) {
        int row = mi * 16 + quad * 4 + r;
        Ts[row * 264 + col] = f2bf(fmaxf(acc[mi][ni][r] + bv, 0.f));
      }
  }
  __syncthreads();

  // ---- stage 2: C = T @ W2 + b2 ----
  constexpr int NI2 = N2 / 64;
  const int wcol = wave * (N2 / 4);
  const unsigned short* gb2 = BT2 + (long long)(wcol + r16) * 256 + kq * 8;
  f32x4 acc2[4][NI2] = {};
  for (int k2 = 0; k2 < 256; k2 += 32) {
#pragma unroll
    for (int c = 0; c < NI2; ++c)
      G2L16(gb2 + (long long)(16 * c) * 256, Bs + (wcol + 16 * c) * 32);
    gb2 += 32;
    __syncthreads();
    bf16x8 af[4], bfr[NI2];
#pragma unroll
    for (int mi = 0; mi < 4; ++mi)
      af[mi] = *(const bf16x8*)(Ts + (mi * 16 + l16) * 264 + k2 + quad * 8);
#pragma unroll
    for (int ni = 0; ni < NI2; ++ni)
      bfr[ni] = *(const bf16x8*)(Bs + (wcol + ni * 16 + l16) * 32 + quad * 8);
#pragma unroll
    for (int mi = 0; mi < 4; ++mi)
#pragma unroll
      for (int ni = 0; ni < NI2; ++ni)
        acc2[mi][ni] = __builtin_amdgcn_mfma_f32_16x16x32_bf16(
            af[mi], bfr[ni], acc2[mi][ni], 0, 0, 0);
    __syncthreads();
  }
#pragma unroll
  for (int ni = 0; ni < NI2; ++ni) {
    int col = wcol + ni * 16 + l16;
    float bv = b2[col];
#pragma unroll
    for (int mi = 0; mi < 4; ++mi)
#pragma unroll
      for (int r = 0; r < 4; ++r) {
        int row = rowBase + mi * 16 + quad * 4 + r;
        if (row < M) {
          float o = acc2[mi][ni][r] + bv;
          if (OUT_BF16)
            ((unsigned short*)Cout)[(long long)row * N2 + col] = f2bf(fmaxf(o, 0.f));
          else
            ((float*)Cout)[(long long)row * N2 + col] = o;
        }
      }
  }
}

// ---------------------------------------------------------------------------
extern "C" void kernel_launch(void* const* d_in, const int* in_sizes, int n_in,
                              void* d_out, int out_size, void* d_ws, size_t ws_size,
                              hipStream_t stream) {
  const float* x   = (const float*)d_in[0];
  const float* W1a = (const float*)d_in[1];
  const float* b1a = (const float*)d_in[2];
  const float* W2a = (const float*)d_in[3];
  const float* b2a = (const float*)d_in[4];
  const float* W1b = (const float*)d_in[5];
  const float* b1b = (const float*)d_in[6];
  const float* W2b = (const float*)d_in[7];
  const float* b2b = (const float*)d_in[8];
  const int*   ei  = (const int*)d_in[9];  // [2,E]: row0=src, row1=dst

  const int Nn = in_sizes[0] / 128;  // 50000
  const int E  = in_sizes[9] / 2;    // 600000
  float* out = (float*)d_out;

  const int nb = (Nn + 255) / 256;  // 196 scan blocks

  // workspace
  unsigned short* h   = (unsigned short*)d_ws;     // N*256 bf16
  unsigned short* g0  = h  + (size_t)Nn * 256;     // N*128
  unsigned short* g1  = g0 + (size_t)Nn * 128;     // N*256
  unsigned short* xb  = g1 + (size_t)Nn * 256;     // N*128
  unsigned short* w1t = xb + (size_t)Nn * 128;     // 256*128
  unsigned short* w2t = w1t + 256 * 128;           // 256*256
  unsigned short* w3t = w2t + 256 * 256;           // 256*256
  unsigned short* w4t = w3t + 256 * 256;           // 128*256
  int* deg  = (int*)(w4t + 128 * 256);  // Nn
  int* flg  = deg + Nn;                 // nb+1 (zeroed with deg by prep)
  int* aggr = flg + nb + 1;             // nb
  int* incl = aggr + nb;                // nb
  int* offs = incl + nb;                // Nn+1
  int* pos  = offs + Nn + 1;            // Nn
  int* esrc = pos + Nn;                 // E (+16 int overshoot pad into ws)

  dim3 blk(256);
  int zn = Nn + nb + 1;  // deg + flg zeroed together (contiguous)
  int zb = (zn + 255) / 256;

  // 1) prep: zero deg+flg, cast x->bf16, weight transposes
  prep<<<zb + 768 + 2048, blk, 0, stream>>>(deg, zn, x, xb,
                                            (long long)Nn * 128 / 4,
                                            W1a, W2a, W1b, W2b,
                                            w1t, w2t, w3t, w4t);
  // 2) degree histogram
  hist<<<(E + 255) / 256, blk, 0, stream>>>(ei, deg, E);
  // 3) single-kernel scan -> offs, pos
  scan_all<<<nb, blk, 0, stream>>>(deg, offs, pos, aggr, incl, flg, Nn, nb);
  // 4) CSR fill
  fill_csr<<<(E + 255) / 256, blk, 0, stream>>>(ei, pos, esrc, E);

  int aggBlocks = (Nn + 3) / 4;
  int mlpBlocks = (Nn + 63) / 64;  // 782

  // 5-6) layer 0
  agg_bf16_128<<<aggBlocks, blk, 0, stream>>>(g0, xb, offs, esrc, Nn);
  fused_mlp<128, 256, true><<<mlpBlocks, blk, 0, stream>>>(
      g0, w1t, b1a, w2t, b2a, h, Nn);
  // 7-8) layer 1
  agg_bf16_256<<<aggBlocks, blk, 0, stream>>>(g1, h, offs, esrc, Nn);
  fused_mlp<256, 128, false><<<mlpBlocks, blk, 0, stream>>>(
      g1, w3t, b1b, w4t, b2b, out, Nn);
}